// Round 1
// baseline (1215.579 us; speedup 1.0000x reference)
//
#include <hip/hip_runtime.h>
#include <hip/hip_bf16.h>
#include <cstddef>

// WITRAN 2D PSGMU encoder, MI355X.
// B=32, rows(Lorig)=48, cols(R)=24, C=32, H=256, L=R+Lorig-1=71, N=R*B=768.
// Per step: gate = [h_row|h_col|x_s] @ W^T (+ mask*Bp), K=544, Ngate=1536,
// then gated update + rolled h_col carry.
// GEMM in bf16 MFMA 16x16x32 with SPLIT W (hi+lo bf16) for near-fp32 W accuracy.
// h carried in fp32 (update math) + bf16 shadow (MFMA A operand).

namespace {
constexpr int H_   = 256;
constexpr int C_   = 32;
constexpr int B_   = 32;
constexpr int R_   = 24;
constexpr int LOR_ = 48;
constexpr int L_   = 71;
constexpr int N_   = 768;   // R*B
constexpr int KH_  = 512;   // 2H
constexpr int KT_  = 544;   // 2H + C
constexpr int NKC_ = 17;    // K chunks of 32
}

typedef __attribute__((ext_vector_type(8))) __bf16 bf16x8;
typedef __attribute__((ext_vector_type(4))) float  f32x4;

__device__ __forceinline__ float fsig(float x)  { return 1.f / (1.f + __expf(-x)); }
__device__ __forceinline__ float ftanhf(float x){ float e = __expf(2.f * x); return 1.f - 2.f / (e + 1.f); }

// ---------------------------------------------------------------------------
// Prep 1: W -> fragment-native split-bf16 layout.
// Wfrag[(((pass*17 + kc)*96 + ltile)*64 + lane)*8 + j8]
//   lane: n0 = lane&15 (gate-col within 16-tile), quad = lane>>4
//   k_global = kc*32 + quad*8 + j8
//   l_global = ltile*16 + n0;  kt = l/96, g = (l%96)/16, kl = l%16
//   gate col j = g*256 + kt*16 + kl
// pass0 = bf16(w), pass1 = bf16(w - float(bf16(w)))
// ---------------------------------------------------------------------------
__global__ __launch_bounds__(256) void prep_w(const float* __restrict__ W,
                                              __hip_bfloat16* __restrict__ Wfrag) {
    int o = blockIdx.x * 256 + threadIdx.x;          // < 2*17*96*64*8 = 1,671,168
    int j8   = o & 7;
    int lane = (o >> 3) & 63;
    int rest = o >> 9;
    int lt    = rest % 96;
    int rest2 = rest / 96;
    int kc   = rest2 % 17;
    int pass = rest2 / 17;
    int n0 = lane & 15, quad = lane >> 4;
    int lg  = lt * 16 + n0;
    int kt  = lg / 96;
    int rem = lg % 96;
    int g  = rem >> 4, kl = rem & 15;
    int j  = g * 256 + kt * 16 + kl;
    int kg = kc * 32 + quad * 8 + j8;
    float w = W[j * KT_ + kg];
    __hip_bfloat16 hi = __float2bfloat16(w);
    if (pass) { w = w - __bfloat162float(hi); hi = __float2bfloat16(w); }
    Wfrag[o] = hi;
}

// ---------------------------------------------------------------------------
// Prep 2: all shifted x slices, bf16.  xall[s][n][c], n = r*32 + b, l = s - r.
// ---------------------------------------------------------------------------
__global__ __launch_bounds__(256) void prep_x(const float* __restrict__ inp,
                                              __hip_bfloat16* __restrict__ xall) {
    int o = blockIdx.x * 256 + threadIdx.x;          // < 71*768*32 = 1,744,896
    int c = o & 31;
    int n = (o >> 5) % N_;
    int s = (o >> 5) / N_;
    int r = n >> 5, b = n & 31;
    int l = s - r;
    float v = 0.f;
    if (l >= 0 && l < LOR_) v = inp[((b * LOR_ + l) * R_ + r) * C_ + c];
    xall[o] = __float2bfloat16(v);
}

// ---------------------------------------------------------------------------
// Step kernel. grid = 192 blocks: kt = bx&15 (16 k-tiles of 16 hidden cols),
// m-tile = bx>>4 (12 tiles of 64 batch rows). 256 threads = 4 waves; wave wv
// owns m rows [mbase+wv*16, +16) x all 96 gate cols of this k-tile slab.
// ---------------------------------------------------------------------------
__global__ __launch_bounds__(256, 1) void step_k(
    const __hip_bfloat16* __restrict__ Wfrag,
    const __hip_bfloat16* __restrict__ xall,
    const __hip_bfloat16* __restrict__ hbf_cur,
    const float*          __restrict__ hf_cur,
    __hip_bfloat16*       __restrict__ hbf_nxt,
    float*                __restrict__ hf_nxt,
    const float*          __restrict__ Bp,
    float* __restrict__ out0, float* __restrict__ out1, float* __restrict__ out2,
    int s)
{
    __shared__ float Gt[64][104];     // gate tile 64m x 96l, pad 104 (bank-safe)

    const int t    = threadIdx.x;
    const int wv   = t >> 6;
    const int lane = t & 63;
    const int n0   = lane & 15;
    const int quad = lane >> 4;
    const int kt    = blockIdx.x & 15;
    const int mbase = (blockIdx.x >> 4) * 64;

    f32x4 acc[6];
#pragma unroll
    for (int g = 0; g < 6; ++g) acc[g] = (f32x4){0.f, 0.f, 0.f, 0.f};

    const int arow = mbase + wv * 16 + n0;           // A-operand row (lane&15 = m)

    for (int kc = 0; kc < NKC_; ++kc) {
        bf16x8 a;
        if (kc < 16) a = *(const bf16x8*)(const void*)(hbf_cur + arow * KH_ + kc * 32 + quad * 8);
        else         a = *(const bf16x8*)(const void*)(xall + (size_t)(s * N_ + arow) * C_ + quad * 8);
#pragma unroll
        for (int g = 0; g < 6; ++g) {
            const int lt = kt * 6 + g;
            bf16x8 bhi = *(const bf16x8*)(const void*)(Wfrag + (size_t)((kc * 96 + lt) * 64 + lane) * 8);
            bf16x8 blo = *(const bf16x8*)(const void*)(Wfrag + (size_t)(((17 + kc) * 96 + lt) * 64 + lane) * 8);
            acc[g] = __builtin_amdgcn_mfma_f32_16x16x32_bf16(a, bhi, acc[g], 0, 0, 0);
            acc[g] = __builtin_amdgcn_mfma_f32_16x16x32_bf16(a, blo, acc[g], 0, 0, 0);
        }
    }

    // D layout: col = lane&15 (gate col within tile), row = quad*4 + reg (m).
#pragma unroll
    for (int g = 0; g < 6; ++g)
#pragma unroll
        for (int reg = 0; reg < 4; ++reg)
            Gt[wv * 16 + quad * 4 + reg][g * 16 + n0] = acc[g][reg];

    __syncthreads();

    // ---- fused update: 64m x 16k pairs, each thread 1 m-row x 4 consecutive k
    const int mm  = t >> 2;
    const int klb = (t & 3) * 4;
    const int n = mbase + mm;
    const int k = kt * 16 + klb;
    const int r = n >> 5, b = n & 31;
    const bool useb = (r <= s) && (s < R_);

    f32x4 gv[6];
#pragma unroll
    for (int g = 0; g < 6; ++g) {
        f32x4 v = *(const f32x4*)(const void*)&Gt[mm][g * 16 + klb];
        f32x4 bp = *(const f32x4*)(const void*)(Bp + g * 256 + k);
        gv[g] = useb ? (v + bp) : v;
    }

    f32x4 hro = *(const f32x4*)(const void*)(hf_cur + (size_t)n * KH_ + k);
    f32x4 hco = *(const f32x4*)(const void*)(hf_cur + (size_t)n * KH_ + 256 + k);

    f32x4 hrv, hcv;
#pragma unroll
    for (int j = 0; j < 4; ++j) {
        float ur = fsig(gv[0][j]);
        float orow = fsig(gv[1][j]);
        float uc = fsig(gv[2][j]);
        float oc = fsig(gv[3][j]);
        float ir = ftanhf(gv[4][j]);
        float ic = ftanhf(gv[5][j]);
        hrv[j] = ftanhf((1.f - ur) * hro[j] + ur * ir) * orow;
        hcv[j] = ftanhf((1.f - uc) * hco[j] + uc * ic) * oc;
    }

    // trace output: out0[n][s][0:256]=h_row, [256:512]=h_col
    float* o0 = out0 + ((size_t)n * L_ + s) * 512;
    *(f32x4*)(void*)(o0 + k)       = hrv;
    *(f32x4*)(void*)(o0 + 256 + k) = hcv;

    // carries: h_row stays at n; h_col rolls by B (slot r -> r+1, wrap)
    int n2 = n + B_; if (n2 >= N_) n2 -= N_;
    *(f32x4*)(void*)(hf_nxt + (size_t)n  * KH_ + k)        = hrv;
    *(f32x4*)(void*)(hf_nxt + (size_t)n2 * KH_ + 256 + k)  = hcv;
#pragma unroll
    for (int j = 0; j < 4; ++j) {
        hbf_nxt[(size_t)n  * KH_ + k + j]       = __float2bfloat16(hrv[j]);
        hbf_nxt[(size_t)n2 * KH_ + 256 + k + j] = __float2bfloat16(hcv[j]);
    }

    // snapshots
    if (s >= LOR_ - 1 && r == s - (LOR_ - 1))
        *(f32x4*)(void*)(out2 + (size_t)(b * R_ + r) * H_ + k) = hrv;       // hidden_row_all[b,0,r,:]
    if (r == R_ - 1 && s >= R_ - 1)
        *(f32x4*)(void*)(out1 + (size_t)(b * LOR_ + (s - (R_ - 1))) * H_ + k) = hcv; // hidden_col_all[b,0,l,:]
}

// ---------------------------------------------------------------------------
extern "C" void kernel_launch(void* const* d_in, const int* in_sizes, int n_in,
                              void* d_out, int out_size, void* d_ws, size_t ws_size,
                              hipStream_t stream) {
    const float* inp = (const float*)d_in[0];
    const float* W   = (const float*)d_in[1];
    const float* Bp  = (const float*)d_in[2];

    float* out0 = (float*)d_out;                       // 768*71*512 = 27,918,336
    float* out1 = out0 + (size_t)N_ * L_ * 512;        // 32*48*256  =    393,216
    float* out2 = out1 + (size_t)B_ * LOR_ * H_;       // 32*24*256  =    196,608

    // workspace layout (all offsets 256B-aligned); total 11,550,720 B
    char* ws = (char*)d_ws;
    __hip_bfloat16* Wfrag = (__hip_bfloat16*)(ws);                 // 3,342,336 B
    __hip_bfloat16* xall  = (__hip_bfloat16*)(ws + 3342336);       // 3,489,792 B
    __hip_bfloat16* hbf0  = (__hip_bfloat16*)(ws + 6832128);       //   786,432 B
    __hip_bfloat16* hbf1  = (__hip_bfloat16*)(ws + 7618560);       //   786,432 B
    float*          hf0   = (float*)(ws + 8404992);                // 1,572,864 B
    float*          hf1   = (float*)(ws + 9977856);                // 1,572,864 B

    // zero-init step-0 carry (ws is poisoned 0xAA before every call)
    hipMemsetAsync(hbf0, 0, 786432, stream);
    hipMemsetAsync(hf0,  0, 1572864, stream);

    prep_w<<<6528, 256, 0, stream>>>(W, Wfrag);
    prep_x<<<6816, 256, 0, stream>>>(inp, xall);

    for (int s = 0; s < L_; ++s) {
        const __hip_bfloat16* hbc = (s & 1) ? hbf1 : hbf0;
        __hip_bfloat16*       hbn = (s & 1) ? hbf0 : hbf1;
        const float*          hfc = (s & 1) ? hf1 : hf0;
        float*                hfn = (s & 1) ? hf0 : hf1;
        step_k<<<192, 256, 0, stream>>>(Wfrag, xall, hbc, hfc, hbn, hfn,
                                        Bp, out0, out1, out2, s);
    }
}